// Round 7
// baseline (224.503 us; speedup 1.0000x reference)
//
#include <hip/hip_runtime.h>
#include <math.h>

// HarmonicCQT via f16 MFMA: out[b,t,k] = |sum_n xpad[t*512+n] * (kr[k,n]+i*ki[k,n])|
//
// Path A (ws >= ~8MB), 2 dispatches, NO global atomics:
//   1. prep_fused : fp32 audio -> padded f16 xp + coalesced B-fragment pack
//                   (16B stores, x4096 pre-scale)  [layouts verified R3-R6]
//   2. cqt_mfma5  : WG = (32-bin group, 64-frame tile, b), 8 waves split the
//                   FULL K-support (exact /8 balance), ping-pong register
//                   double-buffer K-loop, partials merged via LDS ds_add_f32,
//                   magnitude fused -> direct store to out.
// Path B (ws >= ~7.7MB): round-3 LDS-staging MFMA kernel (verified, ~224us).
// Path C: verified fp32 kernel (~370us).
//
// MFMA 16x16x32 layouts (verified rounds 3-6, absmax 4.9e-4):
//   A[m=lane&15][k=(lane>>4)*8+j], B[k=(lane>>4)*8+j][n=lane&15],
//   C/D: col=lane&15, row=(lane>>4)*4+reg.
// bp layout per chunk (32 K-cols, 32 bins): 4096B = 4 regions x 1KB:
//   [sg0 re][sg0 im][sg1 re][sg1 im]; lane l's fragment at halfs [l*8, l*8+8).

namespace {
constexpr int kSR    = 22050;
constexpr int kHop   = 512;
constexpr int kBins  = 168;
constexpr int kT     = 689;
constexpr int kB     = 4;
constexpr int kS     = 352768;
constexpr float kKScale    = 4096.0f;
constexpr float kKScaleInv = 1.0f / 4096.0f;
constexpr int kGroups = 6;            // 6 x 32 bins (g5 partially padded)
// path B layout
constexpr int kTPadB   = 768;
constexpr int kBinPadB = 176;
constexpr int kAccB    = kB * kTPadB * kBinPadB * 2;
}

typedef _Float16 half8 __attribute__((ext_vector_type(8)));
typedef _Float16 half2v __attribute__((ext_vector_type(2)));
typedef float floatx4 __attribute__((ext_vector_type(4)));

struct Jobs {          // path B job table (16-bin groups, 2048 slabs)
  int k0[48];
  int lo[48];
  int hi[48];
  int n;
};

struct JobsA {         // path A: one entry per 32-bin group, full K-support
  int lo[kGroups];     // support start col (256-aligned)
  int nch[kGroups];    // 32-col chunks (all divisible by 8)
  int cbase[kGroups];  // chunk prefix sum
  int total;
};

__device__ inline void atomAddF(float* p, float v) {
  __hip_atomic_fetch_add(p, v, __ATOMIC_RELAXED, __HIP_MEMORY_SCOPE_AGENT);
}

// ---- fused prep: [0,nbx) padded audio | [nbx,nbx+total) B-fragment pack ----
__global__ __launch_bounds__(256) void prep_fused(
    const float* __restrict__ x, const float* __restrict__ kr,
    const float* __restrict__ ki, _Float16* __restrict__ xp,
    _Float16* __restrict__ bp,
    const int pad, const int xps, const int nmax,
    const int nbx, const JobsA jt) {
  int bid = blockIdx.x;
  const int tid = threadIdx.x;

  if (bid < nbx) {
    // --- padded f16 audio ---
    const int halfx = xps >> 1;
    const int gid = bid * 256 + tid;
    if (gid >= kB * halfx) return;
    const int b = gid / halfx;
    const int i = (gid - b * halfx) * 2;
    float v0 = 0.f, v1 = 0.f;
    if (i     >= pad && i     < pad + kS) v0 = x[(size_t)b * kS + (i - pad)];
    if (i + 1 >= pad && i + 1 < pad + kS) v1 = x[(size_t)b * kS + (i + 1 - pad)];
    half2v h; h.x = (_Float16)v0; h.y = (_Float16)v1;
    *(half2v*)&xp[(size_t)b * xps + i] = h;
    return;
  }
  bid -= nbx;

  // --- B-fragment pack: one block per chunk; thread -> one 16B fragment ---
  const int chunk = bid;
  int g = 0;
  #pragma unroll
  for (int j = 1; j < kGroups; ++j)
    if (chunk >= jt.cbase[j]) g = j;
  const int c = chunk - jt.cbase[g];
  const int region = tid >> 6;          // 0..3: sg0re, sg0im, sg1re, sg1im
  const int l      = tid & 63;          // fragment lane
  const int sg   = region >> 1;
  const int isIm = region & 1;
  const int mm   = l & 15;
  const int q16  = l >> 4;
  const int bin  = g * 32 + sg * 16 + mm;
  const int col0 = jt.lo[g] + c * 32 + q16 * 8;
  const float* row = (isIm ? ki : kr) + (size_t)bin * nmax;
  const bool binok = (bin < kBins);
  half8 h;
  #pragma unroll
  for (int j = 0; j < 8; ++j) {
    const int col = col0 + j;
    const bool ok = binok && (col < nmax);
    h[j] = ok ? (_Float16)(row[col] * kKScale) : (_Float16)0.f;
  }
  *(half8*)(bp + (size_t)chunk * 2048 + region * 512 + l * 8) = h;
}

// ---- path A main: 8-wave WG, full-K split, LDS reduce, fused magnitude ----
__global__ __launch_bounds__(512, 2) void cqt_mfma5(
    const _Float16* __restrict__ bp, const _Float16* __restrict__ xp,
    float* __restrict__ out, const int xps, const JobsA jt) {
  __shared__ float ltile[64 * 32 * 2];   // 16 KB: [t_local][bin_local][re/im]

  const int g  = blockIdx.x / 48;        // heavy groups first (g ascending)
  const int r48 = blockIdx.x - g * 48;
  const int fb = r48 >> 2;               // 0..11
  const int b  = r48 & 3;
  const int tid  = threadIdx.x;
  const int wave = tid >> 6;             // 0..7
  const int lane = tid & 63;
  const int m = lane & 15;
  const int q = lane >> 4;
  const int fbase = fb * 64;

  // zero the LDS tile
  #pragma unroll
  for (int i = tid; i < 4096; i += 512) ltile[i] = 0.f;
  __syncthreads();

  // my chunk range: wave w takes [w*C, w*C+C)  (nch divisible by 8)
  const int nch = jt.nch[g];
  const int C = (nch + 7) >> 3;
  const int c0 = wave * C;
  int nc = nch - c0;
  if (nc > C) nc = C;

  if (nc > 0) {
    // per-tile A base pointers, row-clamped to frame 688 (t>=689 discarded)
    const _Float16* ax[4];
    #pragma unroll
    for (int tl = 0; tl < 4; ++tl) {
      int row = fbase + tl * 16 + m;
      if (row > kT - 1) row = kT - 1;
      ax[tl] = xp + (size_t)b * xps + (size_t)row * kHop + q * 8
                  + jt.lo[g] + c0 * 32;
    }
    const _Float16* bq = bp + ((size_t)jt.cbase[g] + c0) * 2048 + lane * 8;

    floatx4 acc[4][2][2];                // [tl][sg][re/im]
    #pragma unroll
    for (int tl = 0; tl < 4; ++tl)
      #pragma unroll
      for (int sg = 0; sg < 2; ++sg)
        #pragma unroll
        for (int ri = 0; ri < 2; ++ri)
          acc[tl][sg][ri] = (floatx4){0.f, 0.f, 0.f, 0.f};

    half8 A0[4], B0[4], A1[4], B1[4];
    auto LOADC = [&](int c, half8* A, half8* B) {
      #pragma unroll
      for (int tl = 0; tl < 4; ++tl)
        A[tl] = *(const half8*)(ax[tl] + c * 32);
      const _Float16* bc = bq + (size_t)c * 2048;
      B[0] = *(const half8*)(bc);
      B[1] = *(const half8*)(bc + 512);
      B[2] = *(const half8*)(bc + 1024);
      B[3] = *(const half8*)(bc + 1536);
    };
    auto STEP = [&](half8* A, half8* B) {
      #pragma unroll
      for (int tl = 0; tl < 4; ++tl) {
        acc[tl][0][0] = __builtin_amdgcn_mfma_f32_16x16x32_f16(A[tl], B[0], acc[tl][0][0], 0, 0, 0);
        acc[tl][0][1] = __builtin_amdgcn_mfma_f32_16x16x32_f16(A[tl], B[1], acc[tl][0][1], 0, 0, 0);
        acc[tl][1][0] = __builtin_amdgcn_mfma_f32_16x16x32_f16(A[tl], B[2], acc[tl][1][0], 0, 0, 0);
        acc[tl][1][1] = __builtin_amdgcn_mfma_f32_16x16x32_f16(A[tl], B[3], acc[tl][1][1], 0, 0, 0);
      }
    };

    LOADC(0, A0, B0);
    int c = 0;
    #pragma unroll 1
    for (; c + 2 < nc; c += 2) {
      LOADC(c + 1, A1, B1);
      STEP(A0, B0);
      LOADC(c + 2, A0, B0);
      STEP(A1, B1);
    }
    if (c + 1 < nc) {            // nc - c == 2
      LOADC(c + 1, A1, B1);
      STEP(A0, B0);
      STEP(A1, B1);
    } else {                     // nc - c == 1
      STEP(A0, B0);
    }

    // merge partials into the shared tile (ds_add_f32, no global traffic)
    #pragma unroll
    for (int tl = 0; tl < 4; ++tl) {
      #pragma unroll
      for (int sg = 0; sg < 2; ++sg) {
        #pragma unroll
        for (int rr = 0; rr < 4; ++rr) {
          const int flat = (((tl * 16 + q * 4 + rr) * 32) + sg * 16 + m) * 2;
          atomicAdd(&ltile[flat],     acc[tl][sg][0][rr]);
          atomicAdd(&ltile[flat + 1], acc[tl][sg][1][rr]);
        }
      }
    }
  }
  __syncthreads();

  // fused magnitude + direct store (each (t,k) owned by exactly one WG)
  #pragma unroll 1
  for (int i = tid; i < 2048; i += 512) {
    const int tl_ = i >> 5;
    const int bl  = i & 31;
    const int t = fbase + tl_;
    const int k = g * 32 + bl;
    if (t < kT && k < kBins) {
      const float re = ltile[i * 2];
      const float im = ltile[i * 2 + 1];
      out[((size_t)b * kT + t) * kBins + k] =
          sqrtf(re * re + im * im) * kKScaleInv;
    }
  }
}

// ================= path B: round-3 LDS-staging MFMA (verified) =============
__global__ __launch_bounds__(256) void prep_x_kernel(
    const float* __restrict__ x, _Float16* __restrict__ xp,
    const int pad, const int xps) {
  const int halfx = xps >> 1;
  int gid = blockIdx.x * 256 + threadIdx.x;
  if (gid >= kB * halfx) return;
  const int b = gid / halfx;
  const int i = (gid - b * halfx) * 2;
  float v0 = 0.f, v1 = 0.f;
  if (i     >= pad && i     < pad + kS) v0 = x[(size_t)b * kS + (i - pad)];
  if (i + 1 >= pad && i + 1 < pad + kS) v1 = x[(size_t)b * kS + (i + 1 - pad)];
  half2v h; h.x = (_Float16)v0; h.y = (_Float16)v1;
  *(half2v*)&xp[(size_t)b * xps + i] = h;
}

__global__ __launch_bounds__(256) void cqt_mfma_kernel(
    const float* __restrict__ kr, const float* __restrict__ ki,
    const _Float16* __restrict__ xp, float* __restrict__ accb,
    const int nmax, const int xps, const Jobs jt) {
  __shared__ _Float16 Bs[2][16][264];
  const int jb = blockIdx.x;
  const int k0   = jt.k0[jb];
  const int n_lo = jt.lo[jb];
  const int n_hi = jt.hi[jb];
  const int b  = blockIdx.z;
  const int fb = blockIdx.y;
  const int tid  = threadIdx.x;
  const int lane = tid & 63;
  const int wave = tid >> 6;
  const int m = lane & 15;
  const int q = lane >> 4;
  const int sbin = tid >> 4;
  const int scol = tid & 15;
  const int gbin = k0 + sbin;
  const bool binok = (gbin < kBins);
  const float* rowr = kr + (size_t)gbin * nmax;
  const float* rowi = ki + (size_t)gbin * nmax;
  const int fbase = fb * 256 + wave * 64;
  const _Float16* ax =
      xp + (size_t)b * xps + (size_t)(fbase + m) * kHop + q * 8;
  floatx4 accr[4], acci[4];
  #pragma unroll
  for (int tl = 0; tl < 4; ++tl) {
    accr[tl] = (floatx4){0.f, 0.f, 0.f, 0.f};
    acci[tl] = (floatx4){0.f, 0.f, 0.f, 0.f};
  }
  for (int n0r = n_lo; n0r < n_hi; n0r += 256) {
    __syncthreads();
    #pragma unroll
    for (int c = 0; c < 16; ++c) {
      const int col = n0r + scol + c * 16;
      const bool ok = binok && (col < nmax);
      const float vr = ok ? rowr[col] : 0.f;
      const float vi = ok ? rowi[col] : 0.f;
      Bs[0][sbin][scol + c * 16] = (_Float16)(vr * kKScale);
      Bs[1][sbin][scol + c * 16] = (_Float16)(vi * kKScale);
    }
    __syncthreads();
    const _Float16* axr = ax + n0r;
    #pragma unroll
    for (int c = 0; c < 8; ++c) {
      const int ko = c * 32 + q * 8;
      const half8 br = *(const half8*)&Bs[0][m][ko];
      const half8 bi = *(const half8*)&Bs[1][m][ko];
      #pragma unroll
      for (int tl = 0; tl < 4; ++tl) {
        const half8 a = *(const half8*)(axr + tl * 16 * kHop + c * 32);
        accr[tl] = __builtin_amdgcn_mfma_f32_16x16x32_f16(a, br, accr[tl], 0, 0, 0);
        acci[tl] = __builtin_amdgcn_mfma_f32_16x16x32_f16(a, bi, acci[tl], 0, 0, 0);
      }
    }
  }
  #pragma unroll
  for (int tl = 0; tl < 4; ++tl) {
    #pragma unroll
    for (int rr = 0; rr < 4; ++rr) {
      const int t = fbase + tl * 16 + q * 4 + rr;
      const size_t o = (((size_t)b * kTPadB + t) * kBinPadB + (k0 + m)) * 2;
      atomAddF(&accb[o],     accr[tl][rr] * kKScaleInv);
      atomAddF(&accb[o + 1], acci[tl][rr] * kKScaleInv);
    }
  }
}

__global__ __launch_bounds__(256) void cqt_mag_final(
    const float* __restrict__ accb, float* __restrict__ out,
    const int tp, const int kp) {
  int gid = blockIdx.x * 256 + threadIdx.x;
  if (gid >= kB * kT * kBins) return;
  const int k = gid % kBins;
  const int r = gid / kBins;
  const int t = r % kT;
  const int b = r / kT;
  const float2 v = ((const float2*)accb)[((size_t)b * tp + t) * kp + k];
  out[gid] = sqrtf(v.x * v.x + v.y * v.y);
}

// ================= path C: verified fp32 kernel (round 2) ==================
namespace fb32 {
constexpr int TT = 8;
constexpr int KG = 4;
constexpr int kTTiles  = (kT + TT - 1) / TT;
constexpr int kKGroups = kBins / KG;
constexpr int kWaves   = kB * kTTiles * kKGroups;
}

__global__ __launch_bounds__(256) void cqt_mag_kernel(
    const float* __restrict__ x,
    const float* __restrict__ kr,
    const float* __restrict__ ki,
    float* __restrict__ out,
    const int nmax, const int pad) {
  using namespace fb32;
  const int wave = (blockIdx.x << 2) + (threadIdx.x >> 6);
  const int lane = threadIdx.x & 63;
  if (wave >= kWaves) return;
  const int kg    = wave / (kB * kTTiles);
  const int rem   = wave - kg * (kB * kTTiles);
  const int b     = rem / kTTiles;
  const int ttile = rem - b * kTTiles;
  const int k0 = kg * KG;
  const int t0 = ttile * TT;
  const double Q  = 1.0 / (exp2(1.0 / 24.0) - 1.0);
  const double f0 = 32.7 * exp2((double)k0 / 24.0);
  int N = (int)ceil(Q * (double)kSR / f0) + 8;
  int full_start = nmax - N;
  if (full_start < 0) full_start = 0;
  int tbase[TT], lo[TT], t_last;
  { int t = t0 + TT - 1; if (t > kT - 1) t = kT - 1; t_last = t; }
  #pragma unroll
  for (int tt = 0; tt < TT; ++tt) {
    int t = t0 + tt; if (t > kT - 1) t = kT - 1;
    tbase[tt] = b * kS + t * kHop - pad;
    lo[tt]    = pad - t * kHop;
  }
  int head_start = pad - t_last * kHop;
  if (head_start < full_start) head_start = full_start;
  int safe = pad - t0 * kHop;
  if (safe < head_start) safe = head_start;
  int body_start = nmax - ((nmax - safe) & ~63);
  float accr[TT][KG], acci[TT][KG];
  #pragma unroll
  for (int tt = 0; tt < TT; ++tt)
    #pragma unroll
    for (int kk = 0; kk < KG; ++kk) { accr[tt][kk] = 0.f; acci[tt][kk] = 0.f; }
  for (int n = body_start - 64; n > head_start - 64; n -= 64) {
    const int nn = n + lane;
    const bool kok = (nn >= 0);
    float krv[KG], kiv[KG];
    #pragma unroll
    for (int kk = 0; kk < KG; ++kk) {
      krv[kk] = kok ? kr[(k0 + kk) * nmax + nn] : 0.f;
      kiv[kk] = kok ? ki[(k0 + kk) * nmax + nn] : 0.f;
    }
    float a[TT];
    #pragma unroll
    for (int tt = 0; tt < TT; ++tt)
      a[tt] = (nn >= lo[tt]) ? x[tbase[tt] + nn] : 0.f;
    #pragma unroll
    for (int tt = 0; tt < TT; ++tt)
      #pragma unroll
      for (int kk = 0; kk < KG; ++kk) {
        accr[tt][kk] = fmaf(a[tt], krv[kk], accr[tt][kk]);
        acci[tt][kk] = fmaf(a[tt], kiv[kk], acci[tt][kk]);
      }
  }
  for (int n = body_start; n < nmax; n += 64) {
    const int nn = n + lane;
    float krv[KG], kiv[KG];
    #pragma unroll
    for (int kk = 0; kk < KG; ++kk) {
      krv[kk] = kr[(k0 + kk) * nmax + nn];
      kiv[kk] = ki[(k0 + kk) * nmax + nn];
    }
    float a[TT];
    #pragma unroll
    for (int tt = 0; tt < TT; ++tt)
      a[tt] = x[tbase[tt] + nn];
    #pragma unroll
    for (int tt = 0; tt < TT; ++tt)
      #pragma unroll
      for (int kk = 0; kk < KG; ++kk) {
        accr[tt][kk] = fmaf(a[tt], krv[kk], accr[tt][kk]);
        acci[tt][kk] = fmaf(a[tt], kiv[kk], acci[tt][kk]);
      }
  }
  #pragma unroll
  for (int tt = 0; tt < TT; ++tt) {
    #pragma unroll
    for (int kk = 0; kk < KG; ++kk) {
      float r = accr[tt][kk];
      float i = acci[tt][kk];
      #pragma unroll
      for (int s = 32; s > 0; s >>= 1) {
        r += __shfl_xor(r, s, 64);
        i += __shfl_xor(i, s, 64);
      }
      if (lane == 0) {
        const int t = t0 + tt;
        if (t < kT)
          out[(b * kT + t) * kBins + (k0 + kk)] = sqrtf(r * r + i * i);
      }
    }
  }
}
// ============================================================================

extern "C" void kernel_launch(void* const* d_in, const int* in_sizes, int n_in,
                              void* d_out, int out_size, void* d_ws, size_t ws_size,
                              hipStream_t stream) {
  const float* x  = (const float*)d_in[0];   // [4, 1, 352768]
  const float* kr = (const float*)d_in[1];   // [168, nmax]
  const float* ki = (const float*)d_in[2];   // [168, nmax]
  float* out = (float*)d_out;                // [4, 1, 689, 168]

  const int nmax = in_sizes[1] / kBins;      // 23013 (runtime truth)
  const int pad  = nmax - kHop;

  const int kcap = ((nmax + 255) / 256) * 256;   // 23040
  const double Q = 1.0 / (exp2(1.0 / 24.0) - 1.0);

  // ---- path A layout ----
  const int xpsA = (kT - 1) * kHop + kcap + 256;           // 375,552
  const size_t xpA_bytes = (size_t)kB * xpsA * sizeof(_Float16);
  const size_t bpA_off   = (xpA_bytes + 511) & ~(size_t)511;

  // ---- path A job table: per 32-bin group, full 256-aligned support ----
  JobsA jA;
  int totA = 0;
  for (int g = 0; g < kGroups; ++g) {
    const double f0 = 32.7 * exp2((double)(32 * g) / 24.0);
    const int N = (int)ceil(Q * (double)kSR / f0) + 8;
    int lo_r = nmax - N;
    if (lo_r < 0) lo_r = 0;
    lo_r &= ~255;
    jA.lo[g]    = lo_r;
    jA.nch[g]   = (kcap - lo_r) / 32;   // all divisible by 8
    jA.cbase[g] = totA;
    totA += jA.nch[g];
  }
  jA.total = totA;   // 1216 expected

  const size_t bpA_bytes = (size_t)totA * 4096;
  const size_t ws_A = bpA_off + bpA_bytes;       // ~8.0 MB

  // ---- path B layout ----
  const int xpsB = (kTPadB - 1) * kHop + kcap + 256;       // 416,000
  const size_t xpB_bytes = (size_t)kB * xpsB * sizeof(_Float16);
  const size_t accB_off  = (xpB_bytes + 511) & ~(size_t)511;
  const size_t accB_bytes = (size_t)kAccB * sizeof(float);
  const size_t ws_B = accB_off + accB_bytes;

  if (ws_size >= ws_A) {
    // ---- path A: 2 dispatches, no global atomics ----
    _Float16* xp = (_Float16*)d_ws;
    _Float16* bp = (_Float16*)((char*)d_ws + bpA_off);

    const int nbx = (kB * (xpsA / 2) + 255) / 256;   // 2934
    prep_fused<<<nbx + jA.total, 256, 0, stream>>>(
        x, kr, ki, xp, bp, pad, xpsA, nmax, nbx, jA);

    cqt_mfma5<<<kGroups * 48, 512, 0, stream>>>(bp, xp, out, xpsA, jA);
    return;
  }

  if (ws_size >= ws_B) {
    // ---- path B (round-3, verified ~224us) ----
    _Float16* xp = (_Float16*)d_ws;
    float* accb  = (float*)((char*)d_ws + accB_off);
    Jobs jt;
    int nj = 0;
    for (int g = 0; g < 11; ++g) {
      const int gk0 = 16 * g;
      const double f0 = 32.7 * exp2((double)gk0 / 24.0);
      const int N = (int)ceil(Q * (double)kSR / f0) + 8;
      int lo = nmax - N;
      if (lo < 0) lo = 0;
      lo = (lo / 2048) * 2048;
      for (int s = lo; s < kcap && nj < 48; s += 2048) {
        jt.k0[nj] = gk0;
        jt.lo[nj] = s;
        jt.hi[nj] = (s + 2048 < kcap) ? s + 2048 : kcap;
        ++nj;
      }
    }
    jt.n = nj;
    hipMemsetAsync(accb, 0, accB_bytes, stream);
    {
      const int total = kB * (xpsB / 2);
      prep_x_kernel<<<(total + 255) / 256, 256, 0, stream>>>(x, xp, pad, xpsB);
    }
    {
      dim3 grid(nj, kTPadB / 256, kB);
      cqt_mfma_kernel<<<grid, 256, 0, stream>>>(kr, ki, xp, accb, nmax, xpsB, jt);
    }
    {
      const int total = kB * kT * kBins;
      cqt_mag_final<<<(total + 255) / 256, 256, 0, stream>>>(
          accb, out, kTPadB, kBinPadB);
    }
    return;
  }

  // ---- path C: fp32 fallback ----
  {
    const int blocks = fb32::kWaves / 4;
    cqt_mag_kernel<<<blocks, 256, 0, stream>>>(x, kr, ki, out, nmax, pad);
  }
}

// Round 8
// 154.270 us; speedup vs baseline: 1.4553x; 1.4553x over previous
//
#include <hip/hip_runtime.h>
#include <math.h>

// HarmonicCQT via f16 MFMA: out[b,t,k] = |sum_n xpad[t*512+n] * (kr[k,n]+i*ki[k,n])|
//
// Path A (ws >= ~11MB), 3 dispatches:
//   1. prep_fused : fp32 audio -> padded f16 xp + B-fragment pack (16-bin
//                   chunks, x4096 pre-scale, verified R3/R4 layout) + zero acc
//   2. cqt_mfma6  : WG = 256 thr / 4 waves on the SAME 64 frames, waves =
//                   4 adjacent 16-bin groups (A shared via L1), balanced
//                   K-slices (<=40 chunks/wave), depth-2 ping-pong with
//                   VGPR headroom, guarded global-atomic split-K combine
//   3. cqt_mag_final : sqrt(re^2+im^2)
// Path B (ws >= ~7.7MB): round-3 LDS-staging MFMA kernel (verified, ~224us).
// Path C: verified fp32 kernel (~370us).
//
// MFMA 16x16x32 layouts (verified rounds 3-7, absmax 4.9e-4):
//   A[m=lane&15][k=(lane>>4)*8+j], B[k=(lane>>4)*8+j][n=lane&15],
//   C/D: col=lane&15, row=(lane>>4)*4+reg.
// bp layout per 16-bin chunk (32 K-cols): 2048B = [64 lanes x 16B re][64 x 16B im]

namespace {
constexpr int kSR    = 22050;
constexpr int kHop   = 512;
constexpr int kBins  = 168;
constexpr int kT     = 689;
constexpr int kB     = 4;
constexpr int kS     = 352768;
constexpr float kKScale    = 4096.0f;
constexpr float kKScaleInv = 1.0f / 4096.0f;
constexpr int kG16 = 11;              // 16-bin groups (g10 = bins 160..167)
constexpr int kAcc = kB * kT * kBins * 2;   // unpadded split-K accumulator
// path B layout
constexpr int kTPadB   = 768;
constexpr int kBinPadB = 176;
constexpr int kAccB    = kB * kTPadB * kBinPadB * 2;
}

typedef _Float16 half8 __attribute__((ext_vector_type(8)));
typedef _Float16 half2v __attribute__((ext_vector_type(2)));
typedef float floatx4 __attribute__((ext_vector_type(4)));

struct Jobs {          // path B job table
  int k0[48];
  int lo[48];
  int hi[48];
  int n;
};

struct JobsC {         // path A tables
  int lo16[kG16];      // support start col per 16-bin group (256-aligned)
  int cb16[kG16];      // chunk-prefix per group (bp indexing)
  int mlo[3];          // macro-group (64-bin) support start col
  int sm[32];          // per slice: macro id
  int slo[32];         // per slice: chunk range [slo,shi) rel. to mlo
  int shi[32];
  int nslices;
  int totch;
};

__device__ inline void atomAddF(float* p, float v) {
  __hip_atomic_fetch_add(p, v, __ATOMIC_RELAXED, __HIP_MEMORY_SCOPE_AGENT);
}

// ---- fused prep: [0,nbx) audio | [nbx,nbx+nbp) bpack | rest zero acc ----
__global__ __launch_bounds__(256) void prep_fused(
    const float* __restrict__ x, const float* __restrict__ kr,
    const float* __restrict__ ki, _Float16* __restrict__ xp,
    _Float16* __restrict__ bp, float* __restrict__ accb,
    const int pad, const int xps, const int nmax,
    const int nbx, const int nbp, const JobsC jt) {
  int bid = blockIdx.x;
  const int tid = threadIdx.x;

  if (bid < nbx) {
    // --- padded f16 audio ---
    const int halfx = xps >> 1;
    const int gid = bid * 256 + tid;
    if (gid >= kB * halfx) return;
    const int b = gid / halfx;
    const int i = (gid - b * halfx) * 2;
    float v0 = 0.f, v1 = 0.f;
    if (i     >= pad && i     < pad + kS) v0 = x[(size_t)b * kS + (i - pad)];
    if (i + 1 >= pad && i + 1 < pad + kS) v1 = x[(size_t)b * kS + (i + 1 - pad)];
    half2v h; h.x = (_Float16)v0; h.y = (_Float16)v1;
    *(half2v*)&xp[(size_t)b * xps + i] = h;
    return;
  }
  bid -= nbx;

  if (bid < nbp) {
    // --- B-fragment pack: 64 threads -> one 16-bin chunk (re+im) ---
    const int chunkid = bid * 4 + (tid >> 6);
    const int lane = tid & 63;
    if (chunkid >= jt.totch) return;
    int g = 0;
    #pragma unroll
    for (int j = 1; j < kG16; ++j)
      if (chunkid >= jt.cb16[j]) g = j;
    const int c = chunkid - jt.cb16[g];
    const int mm = lane & 15;
    const int q  = lane >> 4;
    const int bin  = g * 16 + mm;
    const int col0 = jt.lo16[g] + c * 32 + q * 8;
    const bool binok = (bin < kBins);
    const float* rowr = kr + (size_t)bin * nmax;
    const float* rowi = ki + (size_t)bin * nmax;
    half8 hre, him;
    #pragma unroll
    for (int j = 0; j < 8; ++j) {
      const int col = col0 + j;
      const bool ok = binok && (col < nmax);
      hre[j] = ok ? (_Float16)(rowr[col] * kKScale) : (_Float16)0.f;
      him[j] = ok ? (_Float16)(rowi[col] * kKScale) : (_Float16)0.f;
    }
    _Float16* dst = bp + (size_t)chunkid * 1024 + lane * 8;
    *(half8*)dst = hre;
    *(half8*)(dst + 512) = him;
    return;
  }
  bid -= nbp;

  // --- zero split-K accumulator ---
  const int idx = (bid * 256 + tid) * 4;
  if (idx < kAcc)
    *(floatx4*)&accb[idx] = (floatx4){0.f, 0.f, 0.f, 0.f};
}

// ---- path A main: shared-A 4-wave WG, balanced slices, ping-pong K-loop ----
__global__ __launch_bounds__(256, 4) void cqt_mfma6(
    const _Float16* __restrict__ bp, const _Float16* __restrict__ xp,
    float* __restrict__ accb, const int xps, const JobsC jt) {
  const int sx = blockIdx.y;           // slice
  const int fb = blockIdx.x >> 2;      // 0..11 (64 frames each)
  const int b  = blockIdx.x & 3;
  const int tid  = threadIdx.x;
  const int wave = tid >> 6;           // 0..3 -> 16-bin group within macro
  const int lane = tid & 63;
  const int mm = lane & 15;
  const int q  = lane >> 4;

  const int mac = jt.sm[sx];
  const int g16 = mac * 4 + wave;
  if (g16 >= kG16) return;             // macro 2 has only 3 groups

  // my chunk range: slice range clipped to my group's support
  const int gs = (jt.lo16[g16] - jt.mlo[mac]) >> 5;
  int c_lo = jt.slo[sx];
  if (c_lo < gs) c_lo = gs;
  const int c_hi = jt.shi[sx];
  const int nc = c_hi - c_lo;
  if (nc <= 0) return;

  const int fbase = fb * 64;

  // A base pointers (row-clamped; clamped rows discarded by t-guard)
  const _Float16* ax[4];
  #pragma unroll
  for (int tl = 0; tl < 4; ++tl) {
    int row = fbase + tl * 16 + mm;
    if (row > kT - 1) row = kT - 1;
    ax[tl] = xp + (size_t)b * xps + (size_t)row * kHop + q * 8
                + jt.mlo[mac] + c_lo * 32;
  }
  // B stream (half units; 1024 halfs per chunk: [re 512][im 512])
  const _Float16* bq = bp + (size_t)(jt.cb16[g16] + c_lo - gs) * 1024 + lane * 8;

  floatx4 accr[4], acci[4];
  #pragma unroll
  for (int tl = 0; tl < 4; ++tl) {
    accr[tl] = (floatx4){0.f, 0.f, 0.f, 0.f};
    acci[tl] = (floatx4){0.f, 0.f, 0.f, 0.f};
  }

  half8 A0[4], A1[4], B0[2], B1[2];
  auto LOADC = [&](int c, half8* A, half8* B) {
    #pragma unroll
    for (int tl = 0; tl < 4; ++tl)
      A[tl] = *(const half8*)(ax[tl] + c * 32);
    const _Float16* bc = bq + (size_t)c * 1024;
    B[0] = *(const half8*)(bc);
    B[1] = *(const half8*)(bc + 512);
  };
  auto STEP = [&](half8* A, half8* B) {
    #pragma unroll
    for (int tl = 0; tl < 4; ++tl) {
      accr[tl] = __builtin_amdgcn_mfma_f32_16x16x32_f16(A[tl], B[0], accr[tl], 0, 0, 0);
      acci[tl] = __builtin_amdgcn_mfma_f32_16x16x32_f16(A[tl], B[1], acci[tl], 0, 0, 0);
    }
  };

  LOADC(0, A0, B0);
  int c = 0;
  #pragma unroll 1
  for (; c + 2 < nc; c += 2) {
    LOADC(c + 1, A1, B1);
    STEP(A0, B0);
    LOADC(c + 2, A0, B0);
    STEP(A1, B1);
  }
  if (c + 1 < nc) {          // tail of 2
    LOADC(c + 1, A1, B1);
    STEP(A0, B0);
    STEP(A1, B1);
  } else {                   // tail of 1
    STEP(A0, B0);
  }

  // epilogue: un-scale + guarded split-K atomic combine
  const int bin = g16 * 16 + mm;
  if (bin < kBins) {
    #pragma unroll
    for (int tl = 0; tl < 4; ++tl) {
      const int tb = fbase + tl * 16 + q * 4;
      #pragma unroll
      for (int r = 0; r < 4; ++r) {
        const int t = tb + r;
        if (t < kT) {
          const size_t o = (((size_t)b * kT + t) * kBins + bin) * 2;
          atomAddF(&accb[o],     accr[tl][r] * kKScaleInv);
          atomAddF(&accb[o + 1], acci[tl][r] * kKScaleInv);
        }
      }
    }
  }
}

// ---- final: magnitude (layout-parametric) ----
__global__ __launch_bounds__(256) void cqt_mag_final(
    const float* __restrict__ accb, float* __restrict__ out,
    const int tp, const int kp) {
  int gid = blockIdx.x * 256 + threadIdx.x;
  if (gid >= kB * kT * kBins) return;
  const int k = gid % kBins;
  const int r = gid / kBins;
  const int t = r % kT;
  const int b = r / kT;
  const float2 v = ((const float2*)accb)[((size_t)b * tp + t) * kp + k];
  out[gid] = sqrtf(v.x * v.x + v.y * v.y);
}

// ================= path B: round-3 LDS-staging MFMA (verified) =============
__global__ __launch_bounds__(256) void prep_x_kernel(
    const float* __restrict__ x, _Float16* __restrict__ xp,
    const int pad, const int xps) {
  const int halfx = xps >> 1;
  int gid = blockIdx.x * 256 + threadIdx.x;
  if (gid >= kB * halfx) return;
  const int b = gid / halfx;
  const int i = (gid - b * halfx) * 2;
  float v0 = 0.f, v1 = 0.f;
  if (i     >= pad && i     < pad + kS) v0 = x[(size_t)b * kS + (i - pad)];
  if (i + 1 >= pad && i + 1 < pad + kS) v1 = x[(size_t)b * kS + (i + 1 - pad)];
  half2v h; h.x = (_Float16)v0; h.y = (_Float16)v1;
  *(half2v*)&xp[(size_t)b * xps + i] = h;
}

__global__ __launch_bounds__(256) void cqt_mfma_kernel(
    const float* __restrict__ kr, const float* __restrict__ ki,
    const _Float16* __restrict__ xp, float* __restrict__ accb,
    const int nmax, const int xps, const Jobs jt) {
  __shared__ _Float16 Bs[2][16][264];
  const int jb = blockIdx.x;
  const int k0   = jt.k0[jb];
  const int n_lo = jt.lo[jb];
  const int n_hi = jt.hi[jb];
  const int b  = blockIdx.z;
  const int fb = blockIdx.y;
  const int tid  = threadIdx.x;
  const int lane = tid & 63;
  const int wave = tid >> 6;
  const int m = lane & 15;
  const int q = lane >> 4;
  const int sbin = tid >> 4;
  const int scol = tid & 15;
  const int gbin = k0 + sbin;
  const bool binok = (gbin < kBins);
  const float* rowr = kr + (size_t)gbin * nmax;
  const float* rowi = ki + (size_t)gbin * nmax;
  const int fbase = fb * 256 + wave * 64;
  const _Float16* ax =
      xp + (size_t)b * xps + (size_t)(fbase + m) * kHop + q * 8;
  floatx4 accr[4], acci[4];
  #pragma unroll
  for (int tl = 0; tl < 4; ++tl) {
    accr[tl] = (floatx4){0.f, 0.f, 0.f, 0.f};
    acci[tl] = (floatx4){0.f, 0.f, 0.f, 0.f};
  }
  for (int n0r = n_lo; n0r < n_hi; n0r += 256) {
    __syncthreads();
    #pragma unroll
    for (int c = 0; c < 16; ++c) {
      const int col = n0r + scol + c * 16;
      const bool ok = binok && (col < nmax);
      const float vr = ok ? rowr[col] : 0.f;
      const float vi = ok ? rowi[col] : 0.f;
      Bs[0][sbin][scol + c * 16] = (_Float16)(vr * kKScale);
      Bs[1][sbin][scol + c * 16] = (_Float16)(vi * kKScale);
    }
    __syncthreads();
    const _Float16* axr = ax + n0r;
    #pragma unroll
    for (int c = 0; c < 8; ++c) {
      const int ko = c * 32 + q * 8;
      const half8 br = *(const half8*)&Bs[0][m][ko];
      const half8 bi = *(const half8*)&Bs[1][m][ko];
      #pragma unroll
      for (int tl = 0; tl < 4; ++tl) {
        const half8 a = *(const half8*)(axr + tl * 16 * kHop + c * 32);
        accr[tl] = __builtin_amdgcn_mfma_f32_16x16x32_f16(a, br, accr[tl], 0, 0, 0);
        acci[tl] = __builtin_amdgcn_mfma_f32_16x16x32_f16(a, bi, acci[tl], 0, 0, 0);
      }
    }
  }
  #pragma unroll
  for (int tl = 0; tl < 4; ++tl) {
    #pragma unroll
    for (int rr = 0; rr < 4; ++rr) {
      const int t = fbase + tl * 16 + q * 4 + rr;
      const size_t o = (((size_t)b * kTPadB + t) * kBinPadB + (k0 + m)) * 2;
      atomAddF(&accb[o],     accr[tl][rr] * kKScaleInv);
      atomAddF(&accb[o + 1], acci[tl][rr] * kKScaleInv);
    }
  }
}

// ================= path C: verified fp32 kernel (round 2) ==================
namespace fb32 {
constexpr int TT = 8;
constexpr int KG = 4;
constexpr int kTTiles  = (kT + TT - 1) / TT;
constexpr int kKGroups = kBins / KG;
constexpr int kWaves   = kB * kTTiles * kKGroups;
}

__global__ __launch_bounds__(256) void cqt_mag_kernel(
    const float* __restrict__ x,
    const float* __restrict__ kr,
    const float* __restrict__ ki,
    float* __restrict__ out,
    const int nmax, const int pad) {
  using namespace fb32;
  const int wave = (blockIdx.x << 2) + (threadIdx.x >> 6);
  const int lane = threadIdx.x & 63;
  if (wave >= kWaves) return;
  const int kg    = wave / (kB * kTTiles);
  const int rem   = wave - kg * (kB * kTTiles);
  const int b     = rem / kTTiles;
  const int ttile = rem - b * kTTiles;
  const int k0 = kg * KG;
  const int t0 = ttile * TT;
  const double Q  = 1.0 / (exp2(1.0 / 24.0) - 1.0);
  const double f0 = 32.7 * exp2((double)k0 / 24.0);
  int N = (int)ceil(Q * (double)kSR / f0) + 8;
  int full_start = nmax - N;
  if (full_start < 0) full_start = 0;
  int tbase[TT], lo[TT], t_last;
  { int t = t0 + TT - 1; if (t > kT - 1) t = kT - 1; t_last = t; }
  #pragma unroll
  for (int tt = 0; tt < TT; ++tt) {
    int t = t0 + tt; if (t > kT - 1) t = kT - 1;
    tbase[tt] = b * kS + t * kHop - pad;
    lo[tt]    = pad - t * kHop;
  }
  int head_start = pad - t_last * kHop;
  if (head_start < full_start) head_start = full_start;
  int safe = pad - t0 * kHop;
  if (safe < head_start) safe = head_start;
  int body_start = nmax - ((nmax - safe) & ~63);
  float accr[TT][KG], acci[TT][KG];
  #pragma unroll
  for (int tt = 0; tt < TT; ++tt)
    #pragma unroll
    for (int kk = 0; kk < KG; ++kk) { accr[tt][kk] = 0.f; acci[tt][kk] = 0.f; }
  for (int n = body_start - 64; n > head_start - 64; n -= 64) {
    const int nn = n + lane;
    const bool kok = (nn >= 0);
    float krv[KG], kiv[KG];
    #pragma unroll
    for (int kk = 0; kk < KG; ++kk) {
      krv[kk] = kok ? kr[(k0 + kk) * nmax + nn] : 0.f;
      kiv[kk] = kok ? ki[(k0 + kk) * nmax + nn] : 0.f;
    }
    float a[TT];
    #pragma unroll
    for (int tt = 0; tt < TT; ++tt)
      a[tt] = (nn >= lo[tt]) ? x[tbase[tt] + nn] : 0.f;
    #pragma unroll
    for (int tt = 0; tt < TT; ++tt)
      #pragma unroll
      for (int kk = 0; kk < KG; ++kk) {
        accr[tt][kk] = fmaf(a[tt], krv[kk], accr[tt][kk]);
        acci[tt][kk] = fmaf(a[tt], kiv[kk], acci[tt][kk]);
      }
  }
  for (int n = body_start; n < nmax; n += 64) {
    const int nn = n + lane;
    float krv[KG], kiv[KG];
    #pragma unroll
    for (int kk = 0; kk < KG; ++kk) {
      krv[kk] = kr[(k0 + kk) * nmax + nn];
      kiv[kk] = ki[(k0 + kk) * nmax + nn];
    }
    float a[TT];
    #pragma unroll
    for (int tt = 0; tt < TT; ++tt)
      a[tt] = x[tbase[tt] + nn];
    #pragma unroll
    for (int tt = 0; tt < TT; ++tt)
      #pragma unroll
      for (int kk = 0; kk < KG; ++kk) {
        accr[tt][kk] = fmaf(a[tt], krv[kk], accr[tt][kk]);
        acci[tt][kk] = fmaf(a[tt], kiv[kk], acci[tt][kk]);
      }
  }
  #pragma unroll
  for (int tt = 0; tt < TT; ++tt) {
    #pragma unroll
    for (int kk = 0; kk < KG; ++kk) {
      float r = accr[tt][kk];
      float i = acci[tt][kk];
      #pragma unroll
      for (int s = 32; s > 0; s >>= 1) {
        r += __shfl_xor(r, s, 64);
        i += __shfl_xor(i, s, 64);
      }
      if (lane == 0) {
        const int t = t0 + tt;
        if (t < kT)
          out[(b * kT + t) * kBins + (k0 + kk)] = sqrtf(r * r + i * i);
      }
    }
  }
}
// ============================================================================

extern "C" void kernel_launch(void* const* d_in, const int* in_sizes, int n_in,
                              void* d_out, int out_size, void* d_ws, size_t ws_size,
                              hipStream_t stream) {
  const float* x  = (const float*)d_in[0];   // [4, 1, 352768]
  const float* kr = (const float*)d_in[1];   // [168, nmax]
  const float* ki = (const float*)d_in[2];   // [168, nmax]
  float* out = (float*)d_out;                // [4, 1, 689, 168]

  const int nmax = in_sizes[1] / kBins;      // 23013 (runtime truth)
  const int pad  = nmax - kHop;

  const int kcap = ((nmax + 255) / 256) * 256;   // 23040
  const double Q = 1.0 / (exp2(1.0 / 24.0) - 1.0);

  // ---- path A tables ----
  JobsC jc;
  int tot = 0;
  for (int g = 0; g < kG16; ++g) {
    const double f0 = 32.7 * exp2((double)(16 * g) / 24.0);
    const int N = (int)ceil(Q * (double)kSR / f0) + 8;
    int lo = nmax - N;
    if (lo < 0) lo = 0;
    lo &= ~255;
    jc.lo16[g] = lo;
    jc.cb16[g] = tot;
    tot += (kcap - lo) / 32;
  }
  jc.totch = tot;                        // ~1980 chunks
  const int nsl_m[3] = {18, 4, 1};       // slices per macro-group
  int ns = 0;
  for (int m = 0; m < 3; ++m) {
    jc.mlo[m] = jc.lo16[4 * m];
    const int C = (kcap - jc.mlo[m]) / 32;
    const int n = nsl_m[m];
    const int len = ((C + n - 1) / n + 3) & ~3;
    for (int s = 0; s < n && ns < 32; ++s) {
      const int slo = s * len;
      if (slo >= C) break;
      int shi = slo + len;
      if (shi > C) shi = C;
      jc.sm[ns] = m; jc.slo[ns] = slo; jc.shi[ns] = shi;
      ++ns;
    }
  }
  jc.nslices = ns;                       // 23 expected

  // ---- path A ws layout ----
  const int xpsA = (kT - 1) * kHop + kcap + 256;           // 375,552
  const size_t xpA_bytes = (size_t)kB * xpsA * sizeof(_Float16);
  const size_t accA_off  = (xpA_bytes + 511) & ~(size_t)511;
  const size_t accA_bytes = (size_t)kAcc * sizeof(float);
  const size_t bpA_off   = (accA_off + accA_bytes + 511) & ~(size_t)511;
  const size_t bpA_bytes = (size_t)tot * 2048;
  const size_t ws_A = bpA_off + bpA_bytes;                 // ~11 MB

  // ---- path B layout ----
  const int xpsB = (kTPadB - 1) * kHop + kcap + 256;
  const size_t xpB_bytes = (size_t)kB * xpsB * sizeof(_Float16);
  const size_t accB_off  = (xpB_bytes + 511) & ~(size_t)511;
  const size_t accB_bytes = (size_t)kAccB * sizeof(float);
  const size_t ws_B = accB_off + accB_bytes;

  if (ws_size >= ws_A) {
    // ---- path A ----
    _Float16* xp = (_Float16*)d_ws;
    float* accb  = (float*)((char*)d_ws + accA_off);
    _Float16* bp = (_Float16*)((char*)d_ws + bpA_off);

    const int nbx = (kB * (xpsA / 2) + 255) / 256;   // audio blocks
    const int nbp = (tot + 3) / 4;                   // bpack blocks (4 chunks ea)
    const int nba = (kAcc / 4 + 255) / 256;          // acc-zero blocks
    prep_fused<<<nbx + nbp + nba, 256, 0, stream>>>(
        x, kr, ki, xp, bp, accb, pad, xpsA, nmax, nbx, nbp, jc);

    {
      dim3 grid(48, ns);   // x = fb(12) * b(4); y = balanced slices
      cqt_mfma6<<<grid, 256, 0, stream>>>(bp, xp, accb, xpsA, jc);
    }
    {
      const int total = kB * kT * kBins;
      cqt_mag_final<<<(total + 255) / 256, 256, 0, stream>>>(
          accb, out, kT, kBins);
    }
    return;
  }

  if (ws_size >= ws_B) {
    // ---- path B (round-3, verified ~224us) ----
    _Float16* xp = (_Float16*)d_ws;
    float* accb  = (float*)((char*)d_ws + accB_off);
    Jobs jt;
    int nj = 0;
    for (int g = 0; g < 11; ++g) {
      const int gk0 = 16 * g;
      const double f0 = 32.7 * exp2((double)gk0 / 24.0);
      const int N = (int)ceil(Q * (double)kSR / f0) + 8;
      int lo = nmax - N;
      if (lo < 0) lo = 0;
      lo = (lo / 2048) * 2048;
      for (int s = lo; s < kcap && nj < 48; s += 2048) {
        jt.k0[nj] = gk0;
        jt.lo[nj] = s;
        jt.hi[nj] = (s + 2048 < kcap) ? s + 2048 : kcap;
        ++nj;
      }
    }
    jt.n = nj;
    hipMemsetAsync(accb, 0, accB_bytes, stream);
    {
      const int total = kB * (xpsB / 2);
      prep_x_kernel<<<(total + 255) / 256, 256, 0, stream>>>(x, xp, pad, xpsB);
    }
    {
      dim3 grid(nj, kTPadB / 256, kB);
      cqt_mfma_kernel<<<grid, 256, 0, stream>>>(kr, ki, xp, accb, nmax, xpsB, jt);
    }
    {
      const int total = kB * kT * kBins;
      cqt_mag_final<<<(total + 255) / 256, 256, 0, stream>>>(
          accb, out, kTPadB, kBinPadB);
    }
    return;
  }

  // ---- path C: fp32 fallback ----
  {
    const int blocks = fb32::kWaves / 4;
    cqt_mag_kernel<<<blocks, 256, 0, stream>>>(x, kr, ki, out, nmax, pad);
  }
}

// Round 9
// 129.179 us; speedup vs baseline: 1.7379x; 1.1942x over previous
//
#include <hip/hip_runtime.h>
#include <math.h>

// HarmonicCQT via f16 MFMA: out[b,t,k] = |sum_n xpad[t*512+n] * (kr[k,n]+i*ki[k,n])|
//
// Path A (ws >= ~10.8MB), 3 dispatches:
//   1. prep_fused : fp32 audio -> padded f16 xp + B-fragment pack (16-bin
//                   chunks, x4096 pre-scale, verified R3-R8 layout) + zero acc
//   2. cqt_mfma7  : m97-style async-DMA double-buffered K-loop.
//                   WG = 4 waves x (64 frames x 16 bins), A shared via LDS.
//                   global_load_lds (16B) stages A and B in exact MFMA
//                   fragment order; all ds_reads are base+lane*16 (no bank
//                   conflicts). Balanced K-slices; guarded atomic split-K.
//   3. cqt_mag_final : sqrt(re^2+im^2)
// Path B (ws >= ~7.7MB): round-3 LDS-staging MFMA kernel (verified, ~224us).
// Path C: verified fp32 kernel (~370us).
//
// MFMA 16x16x32 layouts (verified rounds 3-8, absmax 4.9e-4):
//   A[m=lane&15][k=(lane>>4)*8+j], B[k=(lane>>4)*8+j][n=lane&15],
//   C/D: col=lane&15, row=(lane>>4)*4+reg.
// bp layout per 16-bin chunk (32 K-cols): 2048B = [64 lanes x 16B re][64 x 16B im]
// global_load_lds: per-lane GLOBAL gather is fine; LDS side is wave-uniform
// base, lane l lands at base + l*16 (guide m97/m104/m108).

namespace {
constexpr int kSR    = 22050;
constexpr int kHop   = 512;
constexpr int kBins  = 168;
constexpr int kT     = 689;
constexpr int kB     = 4;
constexpr int kS     = 352768;
constexpr float kKScale    = 4096.0f;
constexpr float kKScaleInv = 1.0f / 4096.0f;
constexpr int kG16 = 11;              // 16-bin groups (g10 = bins 160..167)
constexpr int kAcc = kB * kT * kBins * 2;   // unpadded split-K accumulator
// path B layout
constexpr int kTPadB   = 768;
constexpr int kBinPadB = 176;
constexpr int kAccB    = kB * kTPadB * kBinPadB * 2;
}

typedef _Float16 half8 __attribute__((ext_vector_type(8)));
typedef _Float16 half2v __attribute__((ext_vector_type(2)));
typedef float floatx4 __attribute__((ext_vector_type(4)));

struct Jobs {          // path B job table
  int k0[48];
  int lo[48];
  int hi[48];
  int n;
};

struct JobsC {         // path A tables
  int lo16[kG16];      // support start col per 16-bin group (256-aligned)
  int cb16[kG16];      // chunk-prefix per group (bp indexing)
  int mlo[3];          // macro-group (64-bin) support start col
  int sm[12];          // per slice: macro id
  int slo[12];         // per slice: chunk range [slo,shi) rel. to mlo (even)
  int shi[12];
  int ns;
  int totch;
};

__device__ inline void atomAddF(float* p, float v) {
  __hip_atomic_fetch_add(p, v, __ATOMIC_RELAXED, __HIP_MEMORY_SCOPE_AGENT);
}

typedef __attribute__((address_space(3))) unsigned int lds_uint;
typedef __attribute__((address_space(1))) const unsigned int glb_uint;
__device__ __forceinline__ void dma16(const void* g, void* l) {
  __builtin_amdgcn_global_load_lds((glb_uint*)g, (lds_uint*)l, 16, 0, 0);
}

// ---- fused prep: [0,nbx) audio | [nbx,nbx+nbp) bpack | rest zero acc ----
__global__ __launch_bounds__(256) void prep_fused(
    const float* __restrict__ x, const float* __restrict__ kr,
    const float* __restrict__ ki, _Float16* __restrict__ xp,
    _Float16* __restrict__ bp, float* __restrict__ accb,
    const int pad, const int xps, const int nmax,
    const int nbx, const int nbp, const JobsC jt) {
  int bid = blockIdx.x;
  const int tid = threadIdx.x;

  if (bid < nbx) {
    // --- padded f16 audio ---
    const int halfx = xps >> 1;
    const int gid = bid * 256 + tid;
    if (gid >= kB * halfx) return;
    const int b = gid / halfx;
    const int i = (gid - b * halfx) * 2;
    float v0 = 0.f, v1 = 0.f;
    if (i     >= pad && i     < pad + kS) v0 = x[(size_t)b * kS + (i - pad)];
    if (i + 1 >= pad && i + 1 < pad + kS) v1 = x[(size_t)b * kS + (i + 1 - pad)];
    half2v h; h.x = (_Float16)v0; h.y = (_Float16)v1;
    *(half2v*)&xp[(size_t)b * xps + i] = h;
    return;
  }
  bid -= nbx;

  if (bid < nbp) {
    // --- B-fragment pack: 64 threads -> one 16-bin chunk (re+im) ---
    const int chunkid = bid * 4 + (tid >> 6);
    const int lane = tid & 63;
    if (chunkid >= jt.totch) return;
    int g = 0;
    #pragma unroll
    for (int j = 1; j < kG16; ++j)
      if (chunkid >= jt.cb16[j]) g = j;
    const int c = chunkid - jt.cb16[g];
    const int mm = lane & 15;
    const int q  = lane >> 4;
    const int bin  = g * 16 + mm;
    const int col0 = jt.lo16[g] + c * 32 + q * 8;
    const bool binok = (bin < kBins);
    const float* rowr = kr + (size_t)bin * nmax;
    const float* rowi = ki + (size_t)bin * nmax;
    half8 hre, him;
    #pragma unroll
    for (int j = 0; j < 8; ++j) {
      const int col = col0 + j;
      const bool ok = binok && (col < nmax);
      hre[j] = ok ? (_Float16)(rowr[col] * kKScale) : (_Float16)0.f;
      him[j] = ok ? (_Float16)(rowi[col] * kKScale) : (_Float16)0.f;
    }
    _Float16* dst = bp + (size_t)chunkid * 1024 + lane * 8;
    *(half8*)dst = hre;
    *(half8*)(dst + 512) = him;
    return;
  }
  bid -= nbp;

  // --- zero split-K accumulator ---
  const int idx = (bid * 256 + tid) * 4;
  if (idx < kAcc)
    *(floatx4*)&accb[idx] = (floatx4){0.f, 0.f, 0.f, 0.f};
}

// ---- path A main: async-DMA double-buffered MFMA K-loop ----
// LDS per buffer (halfs): A regions [cc(2)][tl(4)] x 512 at 0..4095;
//                         B regions [wave(4)][cc(2)][re/im] x 512 at 4096..12287.
__global__ __launch_bounds__(256) void cqt_mfma7(
    const _Float16* __restrict__ bp, const _Float16* __restrict__ xp,
    float* __restrict__ accb, const int xps, const JobsC jt) {
  __shared__ _Float16 lds[2][12288];   // 2 x 24 KB

  const int sx = blockIdx.y;
  const int fb = blockIdx.x >> 2;      // 0..10
  const int b  = blockIdx.x & 3;
  const int tid  = threadIdx.x;
  const int wave = tid >> 6;
  const int lane = tid & 63;
  const int mm = lane & 15;
  const int q  = lane >> 4;
  const int mac = jt.sm[sx];
  const int g16 = mac * 4 + wave;
  const bool gvalid = (g16 < kG16);
  const int mlo = jt.mlo[mac];
  const int gs = gvalid ? ((jt.lo16[g16] - mlo) >> 5) : 0x7fffffff;
  const int slo = jt.slo[sx];
  const int shi = jt.shi[sx];
  const int fbase = fb * 64;

  // A-DMA source geometry for this wave's 2 staging insts (idx = wave*2+j):
  //   cc = idx>>2, tl = idx&3; lane: row = fbase+tl*16+(lane&15) (clamped),
  //   col = mlo + (c+cc)*32 + (lane>>4)*8.
  const _Float16* xb = xp + (size_t)b * xps;
  const int i0 = wave * 2;
  int aoff[2];      // row*kHop + q*8 (lane-varying), col base added per stage
  #pragma unroll
  for (int j = 0; j < 2; ++j) {
    const int idx = i0 + j;
    const int tl = idx & 3;
    int row = fbase + tl * 16 + mm;
    if (row > kT - 1) row = kT - 1;
    aoff[j] = row * kHop + q * 8 + ((idx >> 2) * 32);
  }
  const _Float16* bgrp =
      gvalid ? (bp + (size_t)(jt.cb16[g16] - gs) * 1024 + lane * 8) : bp;

  floatx4 accr[4], acci[4];
  #pragma unroll
  for (int tl = 0; tl < 4; ++tl) {
    accr[tl] = (floatx4){0.f, 0.f, 0.f, 0.f};
    acci[tl] = (floatx4){0.f, 0.f, 0.f, 0.f};
  }

  auto stageDMA = [&](int c, int buf) {
    _Float16* L = lds[buf];
    // A: 2 insts, fragment-ordered regions; LDS base is wave-uniform,
    // HW scatters lane l at base + l*16B.
    #pragma unroll
    for (int j = 0; j < 2; ++j)
      dma16(xb + mlo + c * 32 + aoff[j], L + (i0 + j) * 512);
    // B: my group's 2 chunks x re/im (contiguous 1KB each from bp)
    if (gvalid && c >= gs) {
      const _Float16* bs = bgrp + (size_t)c * 1024;
      #pragma unroll
      for (int cc = 0; cc < 2; ++cc)
        #pragma unroll
        for (int ri = 0; ri < 2; ++ri)
          dma16(bs + cc * 1024 + ri * 512,
                L + 4096 + (wave * 4 + cc * 2 + ri) * 512);
    }
  };

  auto compute = [&](int c, int buf) {
    if (!gvalid || c < gs) return;
    const _Float16* L = lds[buf];
    #pragma unroll
    for (int cc = 0; cc < 2; ++cc) {
      const half8 Bre = *(const half8*)(L + 4096 + (wave * 4 + cc * 2) * 512 + lane * 8);
      const half8 Bim = *(const half8*)(L + 4096 + (wave * 4 + cc * 2 + 1) * 512 + lane * 8);
      #pragma unroll
      for (int tl = 0; tl < 4; ++tl) {
        const half8 A = *(const half8*)(L + (cc * 4 + tl) * 512 + lane * 8);
        accr[tl] = __builtin_amdgcn_mfma_f32_16x16x32_f16(A, Bre, accr[tl], 0, 0, 0);
        acci[tl] = __builtin_amdgcn_mfma_f32_16x16x32_f16(A, Bim, acci[tl], 0, 0, 0);
      }
    }
  };

  // 2-barrier double-buffered pipeline (m97 structure)
  stageDMA(slo, 0);
  int buf = 0;
  #pragma unroll 1
  for (int c = slo; c < shi; c += 2) {
    __syncthreads();                       // drains this stage's DMA (vmcnt)
    if (c + 2 < shi) stageDMA(c + 2, buf ^ 1);
    compute(c, buf);
    buf ^= 1;
  }

  // epilogue: un-scale + guarded split-K atomic combine (verified R8)
  const int bin = g16 * 16 + mm;
  if (bin < kBins) {
    #pragma unroll
    for (int tl = 0; tl < 4; ++tl) {
      const int tb = fbase + tl * 16 + q * 4;
      #pragma unroll
      for (int r = 0; r < 4; ++r) {
        const int t = tb + r;
        if (t < kT) {
          const size_t o = (((size_t)b * kT + t) * kBins + bin) * 2;
          atomAddF(&accb[o],     accr[tl][r] * kKScaleInv);
          atomAddF(&accb[o + 1], acci[tl][r] * kKScaleInv);
        }
      }
    }
  }
}

// ---- final: magnitude (layout-parametric) ----
__global__ __launch_bounds__(256) void cqt_mag_final(
    const float* __restrict__ accb, float* __restrict__ out,
    const int tp, const int kp) {
  int gid = blockIdx.x * 256 + threadIdx.x;
  if (gid >= kB * kT * kBins) return;
  const int k = gid % kBins;
  const int r = gid / kBins;
  const int t = r % kT;
  const int b = r / kT;
  const float2 v = ((const float2*)accb)[((size_t)b * tp + t) * kp + k];
  out[gid] = sqrtf(v.x * v.x + v.y * v.y);
}

// ================= path B: round-3 LDS-staging MFMA (verified) =============
__global__ __launch_bounds__(256) void prep_x_kernel(
    const float* __restrict__ x, _Float16* __restrict__ xp,
    const int pad, const int xps) {
  const int halfx = xps >> 1;
  int gid = blockIdx.x * 256 + threadIdx.x;
  if (gid >= kB * halfx) return;
  const int b = gid / halfx;
  const int i = (gid - b * halfx) * 2;
  float v0 = 0.f, v1 = 0.f;
  if (i     >= pad && i     < pad + kS) v0 = x[(size_t)b * kS + (i - pad)];
  if (i + 1 >= pad && i + 1 < pad + kS) v1 = x[(size_t)b * kS + (i + 1 - pad)];
  half2v h; h.x = (_Float16)v0; h.y = (_Float16)v1;
  *(half2v*)&xp[(size_t)b * xps + i] = h;
}

__global__ __launch_bounds__(256) void cqt_mfma_kernel(
    const float* __restrict__ kr, const float* __restrict__ ki,
    const _Float16* __restrict__ xp, float* __restrict__ accb,
    const int nmax, const int xps, const Jobs jt) {
  __shared__ _Float16 Bs[2][16][264];
  const int jb = blockIdx.x;
  const int k0   = jt.k0[jb];
  const int n_lo = jt.lo[jb];
  const int n_hi = jt.hi[jb];
  const int b  = blockIdx.z;
  const int fb = blockIdx.y;
  const int tid  = threadIdx.x;
  const int lane = tid & 63;
  const int wave = tid >> 6;
  const int m = lane & 15;
  const int q = lane >> 4;
  const int sbin = tid >> 4;
  const int scol = tid & 15;
  const int gbin = k0 + sbin;
  const bool binok = (gbin < kBins);
  const float* rowr = kr + (size_t)gbin * nmax;
  const float* rowi = ki + (size_t)gbin * nmax;
  const int fbase = fb * 256 + wave * 64;
  const _Float16* ax =
      xp + (size_t)b * xps + (size_t)(fbase + m) * kHop + q * 8;
  floatx4 accr[4], acci[4];
  #pragma unroll
  for (int tl = 0; tl < 4; ++tl) {
    accr[tl] = (floatx4){0.f, 0.f, 0.f, 0.f};
    acci[tl] = (floatx4){0.f, 0.f, 0.f, 0.f};
  }
  for (int n0r = n_lo; n0r < n_hi; n0r += 256) {
    __syncthreads();
    #pragma unroll
    for (int c = 0; c < 16; ++c) {
      const int col = n0r + scol + c * 16;
      const bool ok = binok && (col < nmax);
      const float vr = ok ? rowr[col] : 0.f;
      const float vi = ok ? rowi[col] : 0.f;
      Bs[0][sbin][scol + c * 16] = (_Float16)(vr * kKScale);
      Bs[1][sbin][scol + c * 16] = (_Float16)(vi * kKScale);
    }
    __syncthreads();
    const _Float16* axr = ax + n0r;
    #pragma unroll
    for (int c = 0; c < 8; ++c) {
      const int ko = c * 32 + q * 8;
      const half8 br = *(const half8*)&Bs[0][m][ko];
      const half8 bi = *(const half8*)&Bs[1][m][ko];
      #pragma unroll
      for (int tl = 0; tl < 4; ++tl) {
        const half8 a = *(const half8*)(axr + tl * 16 * kHop + c * 32);
        accr[tl] = __builtin_amdgcn_mfma_f32_16x16x32_f16(a, br, accr[tl], 0, 0, 0);
        acci[tl] = __builtin_amdgcn_mfma_f32_16x16x32_f16(a, bi, acci[tl], 0, 0, 0);
      }
    }
  }
  #pragma unroll
  for (int tl = 0; tl < 4; ++tl) {
    #pragma unroll
    for (int rr = 0; rr < 4; ++rr) {
      const int t = fbase + tl * 16 + q * 4 + rr;
      const size_t o = (((size_t)b * kTPadB + t) * kBinPadB + (k0 + m)) * 2;
      atomAddF(&accb[o],     accr[tl][rr] * kKScaleInv);
      atomAddF(&accb[o + 1], acci[tl][rr] * kKScaleInv);
    }
  }
}

// ================= path C: verified fp32 kernel (round 2) ==================
namespace fb32 {
constexpr int TT = 8;
constexpr int KG = 4;
constexpr int kTTiles  = (kT + TT - 1) / TT;
constexpr int kKGroups = kBins / KG;
constexpr int kWaves   = kB * kTTiles * kKGroups;
}

__global__ __launch_bounds__(256) void cqt_mag_kernel(
    const float* __restrict__ x,
    const float* __restrict__ kr,
    const float* __restrict__ ki,
    float* __restrict__ out,
    const int nmax, const int pad) {
  using namespace fb32;
  const int wave = (blockIdx.x << 2) + (threadIdx.x >> 6);
  const int lane = threadIdx.x & 63;
  if (wave >= kWaves) return;
  const int kg    = wave / (kB * kTTiles);
  const int rem   = wave - kg * (kB * kTTiles);
  const int b     = rem / kTTiles;
  const int ttile = rem - b * kTTiles;
  const int k0 = kg * KG;
  const int t0 = ttile * TT;
  const double Q  = 1.0 / (exp2(1.0 / 24.0) - 1.0);
  const double f0 = 32.7 * exp2((double)k0 / 24.0);
  int N = (int)ceil(Q * (double)kSR / f0) + 8;
  int full_start = nmax - N;
  if (full_start < 0) full_start = 0;
  int tbase[TT], lo[TT], t_last;
  { int t = t0 + TT - 1; if (t > kT - 1) t = kT - 1; t_last = t; }
  #pragma unroll
  for (int tt = 0; tt < TT; ++tt) {
    int t = t0 + tt; if (t > kT - 1) t = kT - 1;
    tbase[tt] = b * kS + t * kHop - pad;
    lo[tt]    = pad - t * kHop;
  }
  int head_start = pad - t_last * kHop;
  if (head_start < full_start) head_start = full_start;
  int safe = pad - t0 * kHop;
  if (safe < head_start) safe = head_start;
  int body_start = nmax - ((nmax - safe) & ~63);
  float accr[TT][KG], acci[TT][KG];
  #pragma unroll
  for (int tt = 0; tt < TT; ++tt)
    #pragma unroll
    for (int kk = 0; kk < KG; ++kk) { accr[tt][kk] = 0.f; acci[tt][kk] = 0.f; }
  for (int n = body_start - 64; n > head_start - 64; n -= 64) {
    const int nn = n + lane;
    const bool kok = (nn >= 0);
    float krv[KG], kiv[KG];
    #pragma unroll
    for (int kk = 0; kk < KG; ++kk) {
      krv[kk] = kok ? kr[(k0 + kk) * nmax + nn] : 0.f;
      kiv[kk] = kok ? ki[(k0 + kk) * nmax + nn] : 0.f;
    }
    float a[TT];
    #pragma unroll
    for (int tt = 0; tt < TT; ++tt)
      a[tt] = (nn >= lo[tt]) ? x[tbase[tt] + nn] : 0.f;
    #pragma unroll
    for (int tt = 0; tt < TT; ++tt)
      #pragma unroll
      for (int kk = 0; kk < KG; ++kk) {
        accr[tt][kk] = fmaf(a[tt], krv[kk], accr[tt][kk]);
        acci[tt][kk] = fmaf(a[tt], kiv[kk], acci[tt][kk]);
      }
  }
  for (int n = body_start; n < nmax; n += 64) {
    const int nn = n + lane;
    float krv[KG], kiv[KG];
    #pragma unroll
    for (int kk = 0; kk < KG; ++kk) {
      krv[kk] = kr[(k0 + kk) * nmax + nn];
      kiv[kk] = ki[(k0 + kk) * nmax + nn];
    }
    float a[TT];
    #pragma unroll
    for (int tt = 0; tt < TT; ++tt)
      a[tt] = x[tbase[tt] + nn];
    #pragma unroll
    for (int tt = 0; tt < TT; ++tt)
      #pragma unroll
      for (int kk = 0; kk < KG; ++kk) {
        accr[tt][kk] = fmaf(a[tt], krv[kk], accr[tt][kk]);
        acci[tt][kk] = fmaf(a[tt], kiv[kk], acci[tt][kk]);
      }
  }
  #pragma unroll
  for (int tt = 0; tt < TT; ++tt) {
    #pragma unroll
    for (int kk = 0; kk < KG; ++kk) {
      float r = accr[tt][kk];
      float i = acci[tt][kk];
      #pragma unroll
      for (int s = 32; s > 0; s >>= 1) {
        r += __shfl_xor(r, s, 64);
        i += __shfl_xor(i, s, 64);
      }
      if (lane == 0) {
        const int t = t0 + tt;
        if (t < kT)
          out[(b * kT + t) * kBins + (k0 + kk)] = sqrtf(r * r + i * i);
      }
    }
  }
}
// ============================================================================

extern "C" void kernel_launch(void* const* d_in, const int* in_sizes, int n_in,
                              void* d_out, int out_size, void* d_ws, size_t ws_size,
                              hipStream_t stream) {
  const float* x  = (const float*)d_in[0];   // [4, 1, 352768]
  const float* kr = (const float*)d_in[1];   // [168, nmax]
  const float* ki = (const float*)d_in[2];   // [168, nmax]
  float* out = (float*)d_out;                // [4, 1, 689, 168]

  const int nmax = in_sizes[1] / kBins;      // 23013 (runtime truth)
  const int pad  = nmax - kHop;

  const int kcap = ((nmax + 255) / 256) * 256;   // 23040
  const double Q = 1.0 / (exp2(1.0 / 24.0) - 1.0);

  // ---- path A tables ----
  JobsC jc;
  int tot = 0;
  for (int g = 0; g < kG16; ++g) {
    const double f0 = 32.7 * exp2((double)(16 * g) / 24.0);
    const int N = (int)ceil(Q * (double)kSR / f0) + 8;
    int lo = nmax - N;
    if (lo < 0) lo = 0;
    lo &= ~255;
    jc.lo16[g] = lo;
    jc.cb16[g] = tot;
    tot += (kcap - lo) / 32;
  }
  jc.totch = tot;                        // ~1980 chunks
  int ns = 0;
  for (int m = 0; m < 3; ++m) {
    jc.mlo[m] = jc.lo16[4 * m];
    const int C = (kcap - jc.mlo[m]) / 32;       // 720 / 120 / 24
    const int nsl = (C + 95) / 96;               // 8 / 2 / 1
    const int len = ((C + nsl - 1) / nsl + 1) & ~1;
    for (int s = 0; s < nsl && ns < 12; ++s) {
      const int lo = s * len;
      if (lo >= C) break;
      int hi = lo + len;
      if (hi > C) hi = C;
      jc.sm[ns] = m; jc.slo[ns] = lo; jc.shi[ns] = hi;
      ++ns;
    }
  }
  jc.ns = ns;                            // 11 expected

  // ---- path A ws layout ----
  const int xpsA = (kT - 1) * kHop + kcap + 256;           // 375,552
  const size_t xpA_bytes = (size_t)kB * xpsA * sizeof(_Float16);
  const size_t accA_off  = (xpA_bytes + 511) & ~(size_t)511;
  const size_t accA_bytes = (size_t)kAcc * sizeof(float);
  const size_t bpA_off   = (accA_off + accA_bytes + 511) & ~(size_t)511;
  const size_t bpA_bytes = (size_t)tot * 2048;
  const size_t ws_A = bpA_off + bpA_bytes;                 // ~10.8 MB

  // ---- path B layout ----
  const int xpsB = (kTPadB - 1) * kHop + kcap + 256;
  const size_t xpB_bytes = (size_t)kB * xpsB * sizeof(_Float16);
  const size_t accB_off  = (xpB_bytes + 511) & ~(size_t)511;
  const size_t accB_bytes = (size_t)kAccB * sizeof(float);
  const size_t ws_B = accB_off + accB_bytes;

  if (ws_size >= ws_A) {
    // ---- path A ----
    _Float16* xp = (_Float16*)d_ws;
    float* accb  = (float*)((char*)d_ws + accA_off);
    _Float16* bp = (_Float16*)((char*)d_ws + bpA_off);

    const int nbx = (kB * (xpsA / 2) + 255) / 256;   // audio blocks
    const int nbp = (tot + 3) / 4;                   // bpack blocks (4 chunks ea)
    const int nba = (kAcc / 4 + 255) / 256;          // acc-zero blocks
    prep_fused<<<nbx + nbp + nba, 256, 0, stream>>>(
        x, kr, ki, xp, bp, accb, pad, xpsA, nmax, nbx, nbp, jc);

    {
      dim3 grid(44, ns);   // x = fb(11) * b(4); y = balanced K-slices
      cqt_mfma7<<<grid, 256, 0, stream>>>(bp, xp, accb, xpsA, jc);
    }
    {
      const int total = kB * kT * kBins;
      cqt_mag_final<<<(total + 255) / 256, 256, 0, stream>>>(
          accb, out, kT, kBins);
    }
    return;
  }

  if (ws_size >= ws_B) {
    // ---- path B (round-3, verified ~224us) ----
    _Float16* xp = (_Float16*)d_ws;
    float* accb  = (float*)((char*)d_ws + accB_off);
    Jobs jt;
    int nj = 0;
    for (int g = 0; g < 11; ++g) {
      const int gk0 = 16 * g;
      const double f0 = 32.7 * exp2((double)gk0 / 24.0);
      const int N = (int)ceil(Q * (double)kSR / f0) + 8;
      int lo = nmax - N;
      if (lo < 0) lo = 0;
      lo = (lo / 2048) * 2048;
      for (int s = lo; s < kcap && nj < 48; s += 2048) {
        jt.k0[nj] = gk0;
        jt.lo[nj] = s;
        jt.hi[nj] = (s + 2048 < kcap) ? s + 2048 : kcap;
        ++nj;
      }
    }
    jt.n = nj;
    hipMemsetAsync(accb, 0, accB_bytes, stream);
    {
      const int total = kB * (xpsB / 2);
      prep_x_kernel<<<(total + 255) / 256, 256, 0, stream>>>(x, xp, pad, xpsB);
    }
    {
      dim3 grid(nj, kTPadB / 256, kB);
      cqt_mfma_kernel<<<grid, 256, 0, stream>>>(kr, ki, xp, accb, nmax, xpsB, jt);
    }
    {
      const int total = kB * kT * kBins;
      cqt_mag_final<<<(total + 255) / 256, 256, 0, stream>>>(
          accb, out, kTPadB, kBinPadB);
    }
    return;
  }

  // ---- path C: fp32 fallback ----
  {
    const int blocks = fb32::kWaves / 4;
    cqt_mag_kernel<<<blocks, 256, 0, stream>>>(x, kr, ki, out, nmax, pad);
  }
}